// Round 12
// baseline (197.187 us; speedup 1.0000x reference)
//
#include <hip/hip_runtime.h>
#include <hip/hip_bf16.h>

typedef int   i32x4 __attribute__((ext_vector_type(4)));
typedef unsigned int   u32;
typedef unsigned short u16;
typedef signed char    i8;

#define TOKENS 8192
#define NDIM   4096
#define KDIM   4096
#define NKT2   32            // K-tiles of 128

// ---------------------------------------------------------------------------
// Kernel 1 (fused, validated): blocks 0..2047 FWHT+q8; 2048..6143 qpack.
// ---------------------------------------------------------------------------
__device__ __forceinline__ u32 pack4(int4 q) {
  return (u32)(q.x & 0xff) | ((u32)(q.y & 0xff) << 8) |
         ((u32)(q.z & 0xff) << 16) | ((u32)(q.w & 0xff) << 24);
}

__global__ __launch_bounds__(256)
void fused_aux(const float* __restrict__ x, i8* __restrict__ xq,
               float* __restrict__ xscale,
               const int* __restrict__ Q, i8* __restrict__ W8) {
  if (blockIdx.x >= 2048) {
    const size_t idx = (((size_t)(blockIdx.x - 2048)) * 256 + threadIdx.x) * 16;
    int4 a = *reinterpret_cast<const int4*>(Q + idx);
    int4 b = *reinterpret_cast<const int4*>(Q + idx + 4);
    int4 c = *reinterpret_cast<const int4*>(Q + idx + 8);
    int4 d = *reinterpret_cast<const int4*>(Q + idx + 12);
    uint4 pk; pk.x = pack4(a); pk.y = pack4(b); pk.z = pack4(c); pk.w = pack4(d);
    *reinterpret_cast<uint4*>(W8 + idx) = pk;
    return;
  }
  const int row = blockIdx.x * 4 + (threadIdx.x >> 6);
  const int l   = threadIdx.x & 63;

  const float4* xv = reinterpret_cast<const float4*>(x + (size_t)row * KDIM) + l * 16;
  float v[64];
#pragma unroll
  for (int j = 0; j < 16; ++j) {
    float4 f = xv[j];
    v[4*j+0] = f.x; v[4*j+1] = f.y; v[4*j+2] = f.z; v[4*j+3] = f.w;
  }

#pragma unroll
  for (int h = 1; h < 64; h <<= 1) {
#pragma unroll
    for (int j = 0; j < 64; ++j) {
      if ((j & h) == 0) {
        float a = v[j], b = v[j + h];
        v[j] = a + b; v[j + h] = a - b;
      }
    }
  }

#pragma unroll
  for (int m = 1; m < 64; m <<= 1) {
    const bool up = (l & m) != 0;
#pragma unroll
    for (int j = 0; j < 64; ++j) {
      float p = __shfl_xor(v[j], m, 64);
      v[j] = up ? (p - v[j]) : (v[j] + p);
    }
  }

  float mxu = 0.f;
#pragma unroll
  for (int j = 0; j < 64; ++j) mxu = fmaxf(mxu, fabsf(v[j]));
#pragma unroll
  for (int m = 1; m < 64; m <<= 1) mxu = fmaxf(mxu, __shfl_xor(mxu, m, 64));
  mxu = fmaxf(mxu, 1e-30f);
  const float inv = 127.0f / mxu;

  i8* orow = xq + (size_t)row * KDIM + l * 64;
#pragma unroll
  for (int g = 0; g < 4; ++g) {
    u32 w[4];
#pragma unroll
    for (int q4 = 0; q4 < 4; ++q4) {
      int b0 = __float2int_rn(v[g*16+q4*4+0] * inv);
      int b1 = __float2int_rn(v[g*16+q4*4+1] * inv);
      int b2 = __float2int_rn(v[g*16+q4*4+2] * inv);
      int b3 = __float2int_rn(v[g*16+q4*4+3] * inv);
      b0 = min(127, max(-127, b0)); b1 = min(127, max(-127, b1));
      b2 = min(127, max(-127, b2)); b3 = min(127, max(-127, b3));
      w[q4] = (u32)(b0 & 0xff) | ((u32)(b1 & 0xff) << 8) |
              ((u32)(b2 & 0xff) << 16) | ((u32)(b3 & 0xff) << 24);
    }
    uint4 pk; pk.x = w[0]; pk.y = w[1]; pk.z = w[2]; pk.w = w[3];
    *reinterpret_cast<uint4*>(orow + g * 16) = pk;
  }
  if (l == 0) xscale[row] = mxu * (0.015625f / 127.0f);
}

// ---------------------------------------------------------------------------
// Kernel 2: int8 GEMM, BK=128 (two verified BK=64 sub-layouts per tile).
// BM=BN=256, 8 waves (2Mx4N), per-wave 128x64, acc[8][4].
// LDS: 2 slots x 64KB; slot = [kk0: A16K|B16K][kk1: A16K|B16K]; each kk-half
// is byte-identical to the R4-verified conflict-free XOR-swizzled layout.
// Per tile (K=128): 4 steps x {4-8 ds_read -> counted lgkm -> 16 MFMA};
// ONE barrier + one free vmcnt(0) (staging issued a full tile earlier).
// ---------------------------------------------------------------------------
__global__ __launch_bounds__(512, 2)
void gemm_bk128(const i8* __restrict__ A, const i8* __restrict__ B,
                const float* __restrict__ xscale, const float* __restrict__ s,
                const float* __restrict__ bias, float* __restrict__ C) {
  __shared__ __align__(16) i8 lds[2 * 65536];   // 128 KB

  const int th   = threadIdx.x;
  const int wave = th >> 6;
  const int lane = th & 63;

  // L2-locality mapping (bijective, 512 blocks)
  const int b0 = blockIdx.x;
  const int xc = b0 & 7;
  const int i  = b0 >> 3;
  const int mt = i >> 1;
  const int nt = xc * 2 + (i & 1);

  const int srow = th >> 2;
  const int scol = ((th & 3) * 16) ^ (((th >> 5) & 1) << 5);
  const i8* gA0 = A + (size_t)(mt * 256 + srow) * KDIM + scol;
  const i8* gA1 = gA0 + (size_t)128 * KDIM;
  const i8* gB0 = B + (size_t)(nt * 256 + srow) * KDIM + scol;
  const i8* gB1 = gB0 + (size_t)128 * KDIM;

  const int ldsA0 = wave * 1024;
  const int ldsA1 = 8192 + wave * 1024;
  const int ldsB0 = 16384 + wave * 1024;
  const int ldsB1 = 24576 + wave * 1024;

  // 8 gloads per tile: kk-half kk at slot*65536 + kk*32768
#define STAGE(tt, ss) do {                                                       \
    _Pragma("unroll")                                                             \
    for (int kk = 0; kk < 2; ++kk) {                                              \
      const size_t go = (size_t)(tt) * 128 + kk * 64;                             \
      i8* ldsbase = lds + (ss) * 65536 + kk * 32768;                              \
      __builtin_amdgcn_global_load_lds(                                           \
        (const __attribute__((address_space(1))) void*)(gA0 + go),                \
        (__attribute__((address_space(3))) void*)(ldsbase + ldsA0), 16, 0, 0);    \
      __builtin_amdgcn_global_load_lds(                                           \
        (const __attribute__((address_space(1))) void*)(gA1 + go),                \
        (__attribute__((address_space(3))) void*)(ldsbase + ldsA1), 16, 0, 0);    \
      __builtin_amdgcn_global_load_lds(                                           \
        (const __attribute__((address_space(1))) void*)(gB0 + go),                \
        (__attribute__((address_space(3))) void*)(ldsbase + ldsB0), 16, 0, 0);    \
      __builtin_amdgcn_global_load_lds(                                           \
        (const __attribute__((address_space(1))) void*)(gB1 + go),                \
        (__attribute__((address_space(3))) void*)(ldsbase + ldsB1), 16, 0, 0);    \
    }                                                                             \
  } while (0)

  const int wm = wave >> 2;
  const int wn = wave & 3;
  const int laneRow = lane & 15;
  const int kByte   = (lane >> 4) << 4;
  const int swz     = ((lane >> 3) & 1) << 5;
  const int aOff = (((wm * 128 + laneRow) * 64 + kByte) ^ swz);
  const int bOff = (((wn * 64 + laneRow) * 64 + kByte) ^ swz) + 16384;

  i32x4 acc[8][4];
#pragma unroll
  for (int mi = 0; mi < 8; ++mi)
#pragma unroll
    for (int ni = 0; ni < 4; ++ni)
      acc[mi][ni] = i32x4{0, 0, 0, 0};

  i32x4 Ax[4], Ay[4], Bx[4], By[4];

  // prologue: stage tiles 0,1; wait tile 0 (tile 1's 8 fly); preload t0/kk0
  STAGE(0, 0);
  STAGE(1, 1);
  asm volatile("s_waitcnt vmcnt(8)" ::: "memory");
  __builtin_amdgcn_sched_barrier(0);
  __builtin_amdgcn_s_barrier();
  {
    const char* k0 = (const char*)lds;
#pragma unroll
    for (int ni = 0; ni < 4; ++ni) Bx[ni] = *(const i32x4*)(k0 + bOff + ni * 1024);
#pragma unroll
    for (int mi = 0; mi < 4; ++mi) Ax[mi] = *(const i32x4*)(k0 + aOff + mi * 1024);
  }

  for (int t = 0; t < NKT2; ++t) {
    const char* k0 = (const char*)lds + (t & 1) * 65536;
    const char* k1 = k0 + 32768;
    const char* ns = (const char*)lds + ((t + 1) & 1) * 65536;

    // ---- step 1: read A(kk0,miH); MFMA (kk0,miL) with Ax,Bx
#pragma unroll
    for (int mi = 0; mi < 4; ++mi)
      Ay[mi] = *(const i32x4*)(k0 + aOff + 4096 + mi * 1024);
    asm volatile("s_waitcnt lgkmcnt(4)" ::: "memory");
    __builtin_amdgcn_sched_barrier(0);
    __builtin_amdgcn_s_setprio(1);
#pragma unroll
    for (int mi = 0; mi < 4; ++mi)
#pragma unroll
      for (int ni = 0; ni < 4; ++ni)
        acc[mi][ni] = __builtin_amdgcn_mfma_i32_16x16x64_i8(Ax[mi], Bx[ni], acc[mi][ni], 0, 0, 0);
    __builtin_amdgcn_s_setprio(0);

    // ---- step 2: read A(kk1,miL) + B(kk1); MFMA (kk0,miH) with Ay,Bx
#pragma unroll
    for (int mi = 0; mi < 4; ++mi)
      Ax[mi] = *(const i32x4*)(k1 + aOff + mi * 1024);
#pragma unroll
    for (int ni = 0; ni < 4; ++ni)
      By[ni] = *(const i32x4*)(k1 + bOff + ni * 1024);
    asm volatile("s_waitcnt lgkmcnt(8)" ::: "memory");
    __builtin_amdgcn_sched_barrier(0);
    __builtin_amdgcn_s_setprio(1);
#pragma unroll
    for (int mi = 0; mi < 4; ++mi)
#pragma unroll
      for (int ni = 0; ni < 4; ++ni)
        acc[mi + 4][ni] = __builtin_amdgcn_mfma_i32_16x16x64_i8(Ay[mi], Bx[ni], acc[mi + 4][ni], 0, 0, 0);
    __builtin_amdgcn_s_setprio(0);

    // ---- step 3: read A(kk1,miH); MFMA (kk1,miL) with Ax,By
#pragma unroll
    for (int mi = 0; mi < 4; ++mi)
      Ay[mi] = *(const i32x4*)(k1 + aOff + 4096 + mi * 1024);
    asm volatile("s_waitcnt lgkmcnt(4)" ::: "memory");
    __builtin_amdgcn_sched_barrier(0);
    __builtin_amdgcn_s_setprio(1);
#pragma unroll
    for (int mi = 0; mi < 4; ++mi)
#pragma unroll
      for (int ni = 0; ni < 4; ++ni)
        acc[mi][ni] = __builtin_amdgcn_mfma_i32_16x16x64_i8(Ax[mi], By[ni], acc[mi][ni], 0, 0, 0);
    __builtin_amdgcn_s_setprio(0);

    // ---- step 4: drain (free), barrier, stage t+2, preload t+1/kk0,
    //              MFMA (kk1,miH) with Ay,By
    asm volatile("s_waitcnt vmcnt(0)" ::: "memory");     // t+1 staged (issued 1 tile ago)
    asm volatile("s_waitcnt lgkmcnt(0)" ::: "memory");   // own slot-t reads done (Ay)
    __builtin_amdgcn_sched_barrier(0);
    __builtin_amdgcn_s_barrier();                        // all waves done with slot t
    if (t + 2 < NKT2) STAGE(t + 2, t & 1);
    if (t + 1 < NKT2) {
#pragma unroll
      for (int ni = 0; ni < 4; ++ni) Bx[ni] = *(const i32x4*)(ns + bOff + ni * 1024);
#pragma unroll
      for (int mi = 0; mi < 4; ++mi) Ax[mi] = *(const i32x4*)(ns + aOff + mi * 1024);
    }
    __builtin_amdgcn_s_setprio(1);
#pragma unroll
    for (int mi = 0; mi < 4; ++mi)
#pragma unroll
      for (int ni = 0; ni < 4; ++ni)
        acc[mi + 4][ni] = __builtin_amdgcn_mfma_i32_16x16x64_i8(Ay[mi], By[ni], acc[mi + 4][ni], 0, 0, 0);
    __builtin_amdgcn_s_setprio(0);
  }
#undef STAGE

  // epilogue: y = acc * (xscale[row] * s[col]) + bias[col]
  const int col0 = nt * 256 + wn * 64 + (lane & 15);
  const int row0 = mt * 256 + wm * 128 + ((lane >> 4) << 2);
  float xs[4][8];
#pragma unroll
  for (int mi = 0; mi < 8; ++mi)
#pragma unroll
    for (int r = 0; r < 4; ++r)
      xs[r][mi] = xscale[row0 + mi * 16 + r];
#pragma unroll
  for (int ni = 0; ni < 4; ++ni) {
    const float sc = s[col0 + ni * 16];
    const float bv = bias[col0 + ni * 16];
#pragma unroll
    for (int mi = 0; mi < 8; ++mi) {
      float* cp = C + (size_t)(row0 + mi * 16) * NDIM + col0 + ni * 16;
#pragma unroll
      for (int r = 0; r < 4; ++r)
        cp[(size_t)r * NDIM] = (float)acc[mi][ni][r] * (xs[r][mi] * sc) + bv;
    }
  }
}

// ---------------------------------------------------------------------------
extern "C" void kernel_launch(void* const* d_in, const int* in_sizes, int n_in,
                              void* d_out, int out_size, void* d_ws, size_t ws_size,
                              hipStream_t stream) {
  (void)in_sizes; (void)n_in; (void)out_size; (void)ws_size;
  const float* x    = (const float*)d_in[0];
  const int*   Q    = (const int*)d_in[1];
  const float* s    = (const float*)d_in[2];
  const float* bias = (const float*)d_in[3];
  float* out = (float*)d_out;

  i8*    xq     = (i8*)d_ws;
  i8*    W8     = xq + (size_t)TOKENS * KDIM;
  float* xscale = (float*)(W8 + (size_t)NDIM * KDIM);

  fused_aux<<<dim3(6144), dim3(256), 0, stream>>>(x, xq, xscale, Q, W8);
  gemm_bk128<<<dim3((TOKENS / 256) * (NDIM / 256)), dim3(512), 0, stream>>>(
      xq, W8, xscale, s, bias, out);
}